// Round 1
// baseline (387.630 us; speedup 1.0000x reference)
//
#include <hip/hip_runtime.h>
#include <hip/hip_bf16.h>

#define DEV __device__ __forceinline__

typedef __bf16 bf16x8 __attribute__((ext_vector_type(8)));
typedef float f32x4 __attribute__((ext_vector_type(4)));
using u16 = unsigned short;

static constexpr int S = 2048;
static constexpr int D = 1024;

DEV u16 f2bf(float f) {
  unsigned u = __builtin_bit_cast(unsigned, f);
  u += 0x7fffu + ((u >> 16) & 1u);
  return (u16)(u >> 16);
}

// ---- fp32 -> bf16 pack (layout preserved) ----
__global__ void k_pack(const float* __restrict__ in, u16* __restrict__ out, int n4) {
  int i = blockIdx.x * blockDim.x + threadIdx.x;
  if (i < n4) {
    const float4 v = reinterpret_cast<const float4*>(in)[i];
    ushort4 o;
    o.x = f2bf(v.x); o.y = f2bf(v.y); o.z = f2bf(v.z); o.w = f2bf(v.w);
    reinterpret_cast<ushort4*>(out)[i] = o;
  }
}

// ---- fp32 [R][C] -> bf16 [C][R] (tiled transpose) ----
__global__ void k_transpose(const float* __restrict__ in, u16* __restrict__ out, int R, int C) {
  __shared__ float t[32][33];
  int c0 = blockIdx.x * 32, r0 = blockIdx.y * 32;
  for (int i = threadIdx.y; i < 32; i += 8)
    t[i][threadIdx.x] = in[(size_t)(r0 + i) * C + c0 + threadIdx.x];
  __syncthreads();
  for (int i = threadIdx.y; i < 32; i += 8)
    out[(size_t)(c0 + i) * R + r0 + threadIdx.x] = f2bf(t[threadIdx.x][i]);
}

// ---- 128x128 bf16 GEMM, C = A[M,K] * Bt[N,K]^T + bias ----
// MODE 0: epilogue routes into Q/K (bf16 [bh][s][64]) and V (bf16 [bh][64][s])
// MODE 1: plain fp32 store
template <int MODE>
__global__ __launch_bounds__(256) void k_gemm(const u16* __restrict__ A, const u16* __restrict__ Bt,
                                              const float* __restrict__ bias, int M, int N, int K,
                                              u16* __restrict__ Qb, u16* __restrict__ Kb,
                                              u16* __restrict__ Vt, float* __restrict__ outF) {
  __shared__ u16 As[128][40];  // +8 pad: b128 frag reads land 2-way (free)
  __shared__ u16 Bs[128][40];
  const int tid = threadIdx.x;
  const int lane = tid & 63, wave = tid >> 6;
  const int l15 = lane & 15, quad = lane >> 4;
  const int m0 = blockIdx.y * 128, n0 = blockIdx.x * 128;
  const int wm = (wave >> 1) * 64, wn = (wave & 1) * 64;

  f32x4 acc[4][4];
#pragma unroll
  for (int i = 0; i < 4; i++)
#pragma unroll
    for (int j = 0; j < 4; j++) acc[i][j] = (f32x4){0.f, 0.f, 0.f, 0.f};

  for (int kk = 0; kk < K; kk += 32) {
    __syncthreads();
#pragma unroll
    for (int ss = 0; ss < 2; ss++) {
      int seg = tid + ss * 256;
      int row = seg >> 2, c = (seg & 3) * 8;
      *reinterpret_cast<uint4*>(&As[row][c]) =
          *reinterpret_cast<const uint4*>(&A[(size_t)(m0 + row) * K + kk + c]);
      *reinterpret_cast<uint4*>(&Bs[row][c]) =
          *reinterpret_cast<const uint4*>(&Bt[(size_t)(n0 + row) * K + kk + c]);
    }
    __syncthreads();
    bf16x8 af[4], bfv[4];
#pragma unroll
    for (int i = 0; i < 4; i++) {
      af[i] = *reinterpret_cast<const bf16x8*>(&As[wm + i * 16 + l15][quad * 8]);
      bfv[i] = *reinterpret_cast<const bf16x8*>(&Bs[wn + i * 16 + l15][quad * 8]);
    }
#pragma unroll
    for (int i = 0; i < 4; i++)
#pragma unroll
      for (int j = 0; j < 4; j++)
        acc[i][j] = __builtin_amdgcn_mfma_f32_16x16x32_bf16(af[i], bfv[j], acc[i][j], 0, 0, 0);
  }

#pragma unroll
  for (int i = 0; i < 4; i++) {
#pragma unroll
    for (int j = 0; j < 4; j++) {
#pragma unroll
      for (int r = 0; r < 4; r++) {
        int m = m0 + wm + i * 16 + quad * 4 + r;  // C layout: row = quad*4+reg
        int n = n0 + wn + j * 16 + l15;           //           col = lane&15
        float v = acc[i][j][r] + bias[n];
        if (MODE == 0) {
          int which = n >> 10;  // block-uniform (128-tiles never straddle 1024 sections)
          int h = (n >> 6) & 15, dh = n & 63;
          int b = m >> 11, s = m & 2047;
          int bh = b * 16 + h;
          if (which == 0)      Qb[((size_t)bh * S + s) * 64 + dh] = f2bf(v);
          else if (which == 1) Kb[((size_t)bh * S + s) * 64 + dh] = f2bf(v);
          else                 Vt[((size_t)bh * 64 + dh) * S + s] = f2bf(v);
        } else {
          outF[(size_t)m * N + n] = v;
        }
      }
    }
  }
}

// ---- flash attention: one block = 64 q-rows of one (b,h); 4 waves x 16 rows ----
__global__ __launch_bounds__(256) void k_attn(const u16* __restrict__ Qb, const u16* __restrict__ Kb,
                                              const u16* __restrict__ Vt, u16* __restrict__ attnB) {
  __shared__ u16 P[4][16][72];  // per-wave P tile, pad 64->72 (2-way on b128 reads)
  const int bh = blockIdx.y;
  const int q0 = blockIdx.x * 64;
  const int tid = threadIdx.x;
  const int lane = tid & 63, wave = tid >> 6;
  const int l15 = lane & 15, quad = lane >> 4;
  const u16* Qh = Qb + (size_t)bh * S * 64;
  const u16* Kh = Kb + (size_t)bh * S * 64;
  const u16* Vh = Vt + (size_t)bh * 64 * S;
  const int qrow = q0 + wave * 16 + l15;
  const bf16x8 aq0 = *reinterpret_cast<const bf16x8*>(&Qh[(size_t)qrow * 64 + quad * 8]);
  const bf16x8 aq1 = *reinterpret_cast<const bf16x8*>(&Qh[(size_t)qrow * 64 + 32 + quad * 8]);

  float mi[4], li[4];
  f32x4 o[4];
#pragma unroll
  for (int r = 0; r < 4; r++) { mi[r] = -1e30f; li[r] = 0.f; }
#pragma unroll
  for (int t = 0; t < 4; t++) o[t] = (f32x4){0.f, 0.f, 0.f, 0.f};

  for (int kb = 0; kb < S / 64; kb++) {
    f32x4 s[4];
#pragma unroll
    for (int nt = 0; nt < 4; nt++) {
      const int krow = kb * 64 + nt * 16 + l15;
      bf16x8 b0 = *reinterpret_cast<const bf16x8*>(&Kh[(size_t)krow * 64 + quad * 8]);
      bf16x8 b1 = *reinterpret_cast<const bf16x8*>(&Kh[(size_t)krow * 64 + 32 + quad * 8]);
      f32x4 z = (f32x4){0.f, 0.f, 0.f, 0.f};
      z = __builtin_amdgcn_mfma_f32_16x16x32_bf16(aq0, b0, z, 0, 0, 0);
      z = __builtin_amdgcn_mfma_f32_16x16x32_bf16(aq1, b1, z, 0, 0, 0);
#pragma unroll
      for (int r = 0; r < 4; r++) s[nt][r] = z[r] * 0.125f;  // 1/sqrt(64)
    }
    // row max over 64 keys (cols live across lane&15; state replicated over those lanes)
    float bm[4];
#pragma unroll
    for (int r = 0; r < 4; r++) bm[r] = fmaxf(fmaxf(s[0][r], s[1][r]), fmaxf(s[2][r], s[3][r]));
#pragma unroll
    for (int off = 1; off < 16; off <<= 1)
#pragma unroll
      for (int r = 0; r < 4; r++) bm[r] = fmaxf(bm[r], __shfl_xor(bm[r], off));
    float mn[4], alpha[4], rs[4];
#pragma unroll
    for (int r = 0; r < 4; r++) {
      mn[r] = fmaxf(mi[r], bm[r]);
      alpha[r] = __expf(mi[r] - mn[r]);  // first iter: exp(-1e30-x) == 0
    }
#pragma unroll
    for (int nt = 0; nt < 4; nt++)
#pragma unroll
      for (int r = 0; r < 4; r++) s[nt][r] = __expf(s[nt][r] - mn[r]);
#pragma unroll
    for (int r = 0; r < 4; r++) rs[r] = (s[0][r] + s[1][r]) + (s[2][r] + s[3][r]);
#pragma unroll
    for (int off = 1; off < 16; off <<= 1)
#pragma unroll
      for (int r = 0; r < 4; r++) rs[r] += __shfl_xor(rs[r], off);
#pragma unroll
    for (int r = 0; r < 4; r++) {
      li[r] = li[r] * alpha[r] + rs[r];
      mi[r] = mn[r];
    }
#pragma unroll
    for (int t = 0; t < 4; t++)
#pragma unroll
      for (int r = 0; r < 4; r++) o[t][r] *= alpha[r];
    // P: C-layout -> LDS -> A-layout (wave-private; DS ops in-order per wave, no barrier)
#pragma unroll
    for (int nt = 0; nt < 4; nt++)
#pragma unroll
      for (int r = 0; r < 4; r++) P[wave][quad * 4 + r][nt * 16 + l15] = f2bf(s[nt][r]);
#pragma unroll
    for (int ks = 0; ks < 2; ks++) {
      bf16x8 ap = *reinterpret_cast<const bf16x8*>(&P[wave][l15][ks * 32 + quad * 8]);
#pragma unroll
      for (int t = 0; t < 4; t++) {
        bf16x8 vb = *reinterpret_cast<const bf16x8*>(
            &Vh[(size_t)(t * 16 + l15) * S + kb * 64 + ks * 32 + quad * 8]);
        o[t] = __builtin_amdgcn_mfma_f32_16x16x32_bf16(ap, vb, o[t], 0, 0, 0);
      }
    }
  }
  const int b = bh >> 4, h = bh & 15;
  const int mbase = b * S + q0 + wave * 16;
#pragma unroll
  for (int r = 0; r < 4; r++) {
    float inv = 1.f / li[r];
#pragma unroll
    for (int t = 0; t < 4; t++)
      attnB[(size_t)(mbase + quad * 4 + r) * D + h * 64 + t * 16 + l15] = f2bf(o[t][r] * inv);
  }
}

extern "C" void kernel_launch(void* const* d_in, const int* in_sizes, int n_in,
                              void* d_out, int out_size, void* d_ws, size_t ws_size,
                              hipStream_t stream) {
  const float* x = (const float*)d_in[0];
  const float* Wqkv = (const float*)d_in[1];
  const float* bqkv = (const float*)d_in[2];
  const float* Wout = (const float*)d_in[3];
  const float* bout = (const float*)d_in[4];
  float* out = (float*)d_out;

  char* p = (char*)d_ws;
  u16* Xb = (u16*)p;    p += (size_t)4096 * 1024 * 2;  // x in bf16 [4096][1024]
  u16* WqkvT = (u16*)p; p += (size_t)3072 * 1024 * 2;  // W_qkv^T bf16 [3072][1024]
  u16* WoutT = (u16*)p; p += (size_t)1024 * 1024 * 2;  // W_out^T bf16 [1024][1024]
  u16* Qb = (u16*)p;    p += (size_t)32 * 2048 * 64 * 2;  // [bh][s][dh]
  u16* Kb = (u16*)p;    p += (size_t)32 * 2048 * 64 * 2;  // [bh][s][dh]
  u16* Vt = (u16*)p;    p += (size_t)32 * 64 * 2048 * 2;  // [bh][dh][s]
  u16* attnB = (u16*)p; p += (size_t)4096 * 1024 * 2;     // attn out bf16 [4096][1024]

  k_pack<<<4096, 256, 0, stream>>>(x, Xb, 4096 * 1024 / 4);
  k_transpose<<<dim3(3072 / 32, 1024 / 32), dim3(32, 8), 0, stream>>>(Wqkv, WqkvT, 1024, 3072);
  k_transpose<<<dim3(1024 / 32, 1024 / 32), dim3(32, 8), 0, stream>>>(Wout, WoutT, 1024, 1024);
  k_gemm<0><<<dim3(3072 / 128, 4096 / 128), 256, 0, stream>>>(Xb, WqkvT, bqkv, 4096, 3072, 1024,
                                                              Qb, Kb, Vt, nullptr);
  k_attn<<<dim3(2048 / 64, 32), 256, 0, stream>>>(Qb, Kb, Vt, attnB);
  k_gemm<1><<<dim3(1024 / 128, 4096 / 128), 256, 0, stream>>>(attnB, WoutT, bout, 4096, 1024, 1024,
                                                              nullptr, nullptr, nullptr, out);
}